// Round 15
// baseline (774.731 us; speedup 1.0000x reference)
//
#include <hip/hip_runtime.h>
#include <hip/hip_fp16.h>
#include <stdint.h>

typedef int v4i  __attribute__((ext_vector_type(4)));
typedef int v16i __attribute__((ext_vector_type(16)));

__device__ __forceinline__ void gld_lds16(const void* g, void* l) {
    __builtin_amdgcn_global_load_lds(
        (const __attribute__((address_space(1))) void*)g,
        (__attribute__((address_space(3))) void*)l,
        16, 0, 0);
}

#define ENDBAR() do { __builtin_amdgcn_s_barrier(); __builtin_amdgcn_sched_barrier(0); } while (0)
#define VMC(n)   asm volatile("s_waitcnt vmcnt(" #n ")" ::: "memory")
#define VMLG0()  asm volatile("s_waitcnt vmcnt(0) lgkmcnt(0)" ::: "memory")

// ---------------- kernel 1: outlier column flags (|x| > 6.0) ----------------
__global__ __launch_bounds__(256) void k_flags(const float* __restrict__ x,
                                               unsigned int* __restrict__ flags,
                                               int total4, int DIN) {
    int idx = blockIdx.x * blockDim.x + threadIdx.x;
    int stride = gridDim.x * blockDim.x;
    int dmask = DIN - 1;  // DIN pow2
    for (int i = idx; i < total4; i += stride) {
        float4 v = ((const float4*)x)[i];
        int base = i * 4;
        if (fabsf(v.x) > 6.0f) atomicOr(&flags[(base + 0) & dmask], 1u);
        if (fabsf(v.y) > 6.0f) atomicOr(&flags[(base + 1) & dmask], 1u);
        if (fabsf(v.z) > 6.0f) atomicOr(&flags[(base + 2) & dmask], 1u);
        if (fabsf(v.w) > 6.0f) atomicOr(&flags[(base + 3) & dmask], 1u);
    }
}

// ------- kernel 2: byte mask + deterministic ascending compaction -------
__global__ __launch_bounds__(256) void k_build(const unsigned int* __restrict__ flags,
                                               unsigned char* __restrict__ bmask,
                                               int* __restrict__ ncols,
                                               int* __restrict__ cols, int DIN) {
    __shared__ int wcnt[4];
    __shared__ int base;
    int tid = threadIdx.x, lane = tid & 63, wid = tid >> 6;
    if (tid == 0) base = 0;
    __syncthreads();
    for (int c0 = 0; c0 < DIN; c0 += 256) {
        int c = c0 + tid;
        bool p = (c < DIN) && (flags[c] != 0u);
        if (c < DIN) bmask[c] = p ? 1 : 0;
        unsigned long long m = __ballot(p);
        int wpre = __popcll(m & ((1ull << lane) - 1ull));
        if (lane == 0) wcnt[wid] = __popcll(m);
        __syncthreads();
        int pre = 0;
        for (int w = 0; w < wid; w++) pre += wcnt[w];
        if (p) cols[base + pre + wpre] = c;
        __syncthreads();
        if (tid == 0) base += wcnt[0] + wcnt[1] + wcnt[2] + wcnt[3];
        __syncthreads();
    }
    if (tid == 0) *ncols = base;
}

// ------- kernel 3: per-row activation quant + fused Xout panel gather -------
__global__ __launch_bounds__(256) void k_quantx(const float* __restrict__ x,
                                                const unsigned char* __restrict__ bmask,
                                                signed char* __restrict__ Xq,
                                                float* __restrict__ sx,
                                                float* __restrict__ Xout,
                                                const int* __restrict__ ncols,
                                                const int* __restrict__ cols, int DIN) {
    int row = blockIdx.x;
    int tid = threadIdx.x, lane = tid & 63, wid = tid >> 6;
    const float* xr = x + (size_t)row * DIN;
    float f[16];
    #pragma unroll
    for (int j = 0; j < 4; j++) {
        float4 v = ((const float4*)xr)[tid * 4 + j];
        f[4*j] = v.x; f[4*j+1] = v.y; f[4*j+2] = v.z; f[4*j+3] = v.w;
    }
    uint4 bm4 = ((const uint4*)bmask)[tid];
    const unsigned char* bm = (const unsigned char*)&bm4;
    float m = 0.0f;
    #pragma unroll
    for (int j = 0; j < 16; j++) {
        if (bm[j]) f[j] = 0.0f;
        m = fmaxf(m, fabsf(f[j]));
    }
    #pragma unroll
    for (int off = 32; off >= 1; off >>= 1) m = fmaxf(m, __shfl_xor(m, off));
    __shared__ float red[4];
    if (lane == 0) red[wid] = m;
    __syncthreads();
    m = fmaxf(fmaxf(red[0], red[1]), fmaxf(red[2], red[3]));
    float sxv = fmaxf(m, 1e-8f);
    if (Xq) {
        float scale = 127.0f / sxv;
        int qi[16];
        #pragma unroll
        for (int j = 0; j < 16; j++) {
            float r = rintf(f[j] * scale);
            r = fminf(127.0f, fmaxf(-127.0f, r));
            qi[j] = (int)r;
        }
        int4 ov;
        ov.x = (qi[0]&0xff) | ((qi[1]&0xff)<<8) | ((qi[2]&0xff)<<16) | ((qi[3]&0xff)<<24);
        ov.y = (qi[4]&0xff) | ((qi[5]&0xff)<<8) | ((qi[6]&0xff)<<16) | ((qi[7]&0xff)<<24);
        ov.z = (qi[8]&0xff) | ((qi[9]&0xff)<<8) | ((qi[10]&0xff)<<16) | ((qi[11]&0xff)<<24);
        ov.w = (qi[12]&0xff) | ((qi[13]&0xff)<<8) | ((qi[14]&0xff)<<16) | ((qi[15]&0xff)<<24);
        ((int4*)(Xq + (size_t)row * DIN))[tid] = ov;
    }
    if (tid < 16) {
        int nc = *ncols;
        int ncl = nc < 16 ? nc : 16;
        float v = 0.0f;
        if (tid < ncl) v = xr[cols[tid]];       // row L1-hot; original (unzeroed) x
        Xout[(size_t)row * 16 + tid] = v;
    }
    if (tid == 0) sx[row] = sxv;
}

// ------- kernel 4: per-output-row weight quant + fused Wout panel gather -------
__global__ __launch_bounds__(256) void k_quantw(const float* __restrict__ CB,
                                                const float* __restrict__ SCB,
                                                signed char* __restrict__ Wq,
                                                float* __restrict__ sw,
                                                float* __restrict__ Wout,
                                                const int* __restrict__ ncols,
                                                const int* __restrict__ cols, int DIN) {
    int row = blockIdx.x;
    int tid = threadIdx.x, lane = tid & 63, wid = tid >> 6;
    float scb = SCB[row];
    const float* cr = CB + (size_t)row * DIN;
    float w[16];
    #pragma unroll
    for (int j = 0; j < 4; j++) {
        float4 v = ((const float4*)cr)[tid * 4 + j];
        w[4*j]   = v.x * scb / 127.0f;
        w[4*j+1] = v.y * scb / 127.0f;
        w[4*j+2] = v.z * scb / 127.0f;
        w[4*j+3] = v.w * scb / 127.0f;
    }
    float m = 0.0f;
    #pragma unroll
    for (int j = 0; j < 16; j++) m = fmaxf(m, fabsf(w[j]));
    #pragma unroll
    for (int off = 32; off >= 1; off >>= 1) m = fmaxf(m, __shfl_xor(m, off));
    __shared__ float red[4];
    if (lane == 0) red[wid] = m;
    __syncthreads();
    m = fmaxf(fmaxf(red[0], red[1]), fmaxf(red[2], red[3]));
    float swv = fmaxf(m, 1e-8f);
    if (Wq) {
        float scale = 127.0f / swv;
        int qi[16];
        #pragma unroll
        for (int j = 0; j < 16; j++) {
            float r = rintf(w[j] * scale);
            r = fminf(127.0f, fmaxf(-127.0f, r));
            qi[j] = (int)r;
        }
        int4 ov;
        ov.x = (qi[0]&0xff) | ((qi[1]&0xff)<<8) | ((qi[2]&0xff)<<16) | ((qi[3]&0xff)<<24);
        ov.y = (qi[4]&0xff) | ((qi[5]&0xff)<<8) | ((qi[6]&0xff)<<16) | ((qi[7]&0xff)<<24);
        ov.z = (qi[8]&0xff) | ((qi[9]&0xff)<<8) | ((qi[10]&0xff)<<16) | ((qi[11]&0xff)<<24);
        ov.w = (qi[12]&0xff) | ((qi[13]&0xff)<<8) | ((qi[14]&0xff)<<16) | ((qi[15]&0xff)<<24);
        ((int4*)(Wq + (size_t)row * DIN))[tid] = ov;
    }
    if (tid < 16) {
        int nc = *ncols;
        int ncl = nc < 16 ? nc : 16;
        float v = 0.0f;
        if (tid < ncl) v = cr[cols[tid]] * scb / 127.0f;   // row L1-hot
        Wout[(size_t)row * 16 + tid] = v;
    }
    if (tid == 0) sw[row] = swv;
}

// -- kernel 5: 256x256 int8 GEMM, R10 skeleton, mfma_i32_32x32x32_i8 --
__global__ __launch_bounds__(512) void k_gemm32(
    const signed char* __restrict__ Xq, const signed char* __restrict__ Wq,
    const float* __restrict__ sx, const float* __restrict__ sw,
    const float* __restrict__ x, const float* __restrict__ CB,
    const float* __restrict__ SCB, const float* __restrict__ bias,
    const float* __restrict__ Xout, const float* __restrict__ Wout,
    const int* __restrict__ ncols, const int* __restrict__ cols,
    float* __restrict__ out, int Nrows, int DOUT, int DIN)
{
    // A: [buf][256 rows][128B], swizzle: 16B-slot s stored at s ^ ((row>>1)&7). B at +65536.
    __shared__ __align__(16) char LDS[131072];

    const int tid = threadIdx.x, lane = tid & 63, wid = tid >> 6;
    const int wm = wid >> 2, wn = wid & 3;     // 2x4 wave grid; 128x64 per wave
    const int hi = lane >> 5;

    int nwg = gridDim.x, bid = blockIdx.x;
    int swzb;
    if ((nwg & 7) == 0) { int cpx = nwg >> 3; swzb = (bid & 7) * cpx + (bid >> 3); }
    else swzb = bid;
    int mtiles = Nrows >> 8;
    int ntiles = DOUT >> 8;
    int mt, ntl;
    if ((mtiles & 7) == 0 && (ntiles & 3) == 0 && (nwg & 31) == 0) {
        // 32 co-resident blocks per XCD form an 8x4 (mt x ntl) rectangle for L2 reuse
        int group = swzb >> 5, local = swzb & 31;
        int mrects = mtiles >> 3;
        int mt_r = group % mrects, nt_r = group / mrects;
        mt  = (mt_r << 3) + (local & 7);
        ntl = (nt_r << 2) + (local >> 3);
    } else { mt = swzb % mtiles; ntl = swzb / mtiles; }
    int brow = mt << 8, bcol = ntl << 8;

    // ds-read lane constants (32x32 fragments): row = base + (lane&31),
    // logical 16B slot = 2*ks + hi, phys = slot ^ ((row>>1)&7) = slot ^ ((lane>>1)&7)
    const int sw7 = (lane >> 1) & 7;
    int o[4];
    #pragma unroll
    for (int ks = 0; ks < 4; ks++) o[ks] = 16 * (((ks << 1) | hi) ^ sw7);
    int aR[4], bR[2];
    #pragma unroll
    for (int mi = 0; mi < 4; mi++) aR[mi] = (wm * 128 + mi * 32 + (lane & 31)) * 128;
    #pragma unroll
    for (int ni = 0; ni < 2; ni++) bR[ni] = 65536 + (wn * 64 + ni * 32 + (lane & 31)) * 128;

    // stage: LDS dest linear; global source pre-swizzled with the same involution
    const int stRow = wid * 8 + (lane >> 3);
    const int stCol = 16 * ((lane & 7) ^ (((wid & 1) << 2) + (lane >> 4)));
    const signed char* aSrc = Xq + (size_t)(brow + stRow) * DIN + stCol;
    const signed char* bSrc = Wq + (size_t)(bcol + stRow) * DIN + stCol;
    const int ldsW = wid * 1024;

    v16i acc[4][2] = {};
    v4i aF[16], bW[4];

    const int nt = DIN >> 7;      // 128-byte K-tiles
    const int NIT = nt >> 1;      // 2 tiles per iteration

#define STAGE_HALF(srcBase, matOff, bf, h, kc)                                   \
    do { _Pragma("unroll")                                                        \
      for (int q = 0; q < 2; q++) {                                               \
        int seg = 2*(h) + q;                                                      \
        gld_lds16((srcBase) + (size_t)seg * 64 * DIN + (kc),                      \
                  &LDS[(matOff) + (bf)*32768 + seg*8192 + ldsW]);                 \
      }                                                                           \
    } while (0)

#define READ_A(bf)                                                                \
    do { _Pragma("unroll")                                                        \
      for (int mi = 0; mi < 4; mi++) { _Pragma("unroll")                          \
        for (int ks = 0; ks < 4; ks++)                                            \
          aF[mi*4+ks] = *(const v4i*)&LDS[(bf)*32768 + aR[mi] + o[ks]];           \
      }                                                                           \
    } while (0)

#define READ_B(bf, ksB)                                                           \
    do { _Pragma("unroll")                                                        \
      for (int ni = 0; ni < 2; ni++) { _Pragma("unroll")                          \
        for (int dk = 0; dk < 2; dk++)                                            \
          bW[ni*2+dk] = *(const v4i*)&LDS[(bf)*32768 + bR[ni] + o[(ksB)+dk]];     \
      }                                                                           \
    } while (0)

#define MFMA16(ksB)                                                               \
    do { __builtin_amdgcn_s_setprio(1); _Pragma("unroll")                         \
      for (int mi = 0; mi < 4; mi++) { _Pragma("unroll")                          \
        for (int ni = 0; ni < 2; ni++) { _Pragma("unroll")                        \
          for (int dk = 0; dk < 2; dk++)                                          \
            acc[mi][ni] = __builtin_amdgcn_mfma_i32_32x32x32_i8(                  \
                aF[mi*4+(ksB)+dk], bW[ni*2+dk], acc[mi][ni], 0, 0, 0);            \
        } }                                                                       \
      __builtin_amdgcn_s_setprio(0);                                              \
    } while (0)

    // ---- prologue: tile0 -> buf0, A(1) -> buf1; leave A(1) in flight ----
    STAGE_HALF(aSrc, 0,     0, 0, 0);
    STAGE_HALF(aSrc, 0,     0, 1, 0);
    STAGE_HALF(bSrc, 65536, 0, 0, 0);
    STAGE_HALF(bSrc, 65536, 0, 1, 0);
    STAGE_HALF(aSrc, 0,     1, 0, 128);
    STAGE_HALF(aSrc, 0,     1, 1, 128);
    VMC(4);
    ENDBAR();

    for (int it = 0; it < NIT; ++it) {
        int t = 2 * it;
        int kB1 = (t + 1) << 7;
        int tA2 = t + 2; if (tA2 > nt - 1) tA2 = nt - 1;
        int kA2 = tA2 << 7;
        int tA3 = t + 3; if (tA3 > nt - 1) tA3 = nt - 1;
        int kA3 = tA3 << 7;

        // W1 (tile t, buf0, ks 0-1); stage B(t+1)->buf1 (disjoint buffer)
        STAGE_HALF(bSrc, 65536, 1, 0, kB1);
        READ_A(0); READ_B(0, 0);
        MFMA16(0);
        STAGE_HALF(bSrc, 65536, 1, 1, kB1);
        ENDBAR();
        // W2 (tile t, buf0, ks 2-3); stage A(t+2)->buf0 A-region (reads are B-region)
        STAGE_HALF(aSrc, 0, 0, 0, kA2);
        READ_B(0, 2);
        MFMA16(2);
        STAGE_HALF(aSrc, 0, 0, 1, kA2);
        VMC(4);
        ENDBAR();
        // W3 (tile t+1, buf1, ks 0-1); stage B(t+2)->buf0
        STAGE_HALF(bSrc, 65536, 0, 0, kA2);
        READ_A(1); READ_B(1, 0);
        MFMA16(0);
        STAGE_HALF(bSrc, 65536, 0, 1, kA2);
        ENDBAR();
        // W4 (tile t+1, buf1, ks 2-3); stage A(t+3)->buf1 A-region
        STAGE_HALF(aSrc, 0, 1, 0, kA3);
        READ_B(1, 2);
        MFMA16(2);
        STAGE_HALF(aSrc, 0, 1, 1, kA3);
        VMC(4);
        ENDBAR();
    }
    VMLG0();
    ENDBAR();

    // ---- epilogue: rank-ncl outlier update; 32x32 D layout ----
    // D: col = lane&31 (output col), row = (reg&3) + 8*(reg>>2) + 4*hi
    int nc = *ncols;
    int ncl = nc < 16 ? nc : 16;
    float* Xo = (float*)&LDS[0];            // [256][17]
    float* Wo = (float*)&LDS[65536];        // [256][17]
    for (int idx = tid; idx < 4096; idx += 512) {
        int i = idx >> 4, c = idx & 15;
        Xo[i * 17 + c] = Xout[(size_t)(brow + i) * 16 + c];
        Wo[i * 17 + c] = Wout[(size_t)(bcol + i) * 16 + c];
    }
    __syncthreads();

    float sww[2], bzz[2];
    #pragma unroll
    for (int ni = 0; ni < 2; ni++) {
        int gcol = bcol + wn * 64 + ni * 32 + (lane & 31);
        sww[ni] = sw[gcol];
        bzz[ni] = bias[gcol];
    }

    #pragma unroll
    for (int mi = 0; mi < 4; mi++) {
        float sxr[16];
        #pragma unroll
        for (int rg = 0; rg < 16; rg++) {
            int rowD = (rg & 3) + 8 * (rg >> 2) + 4 * hi;
            sxr[rg] = sx[brow + wm * 128 + mi * 32 + rowD];
        }
        float vout[2][16];
        #pragma unroll
        for (int ni = 0; ni < 2; ni++)
            #pragma unroll
            for (int rg = 0; rg < 16; rg++)
                vout[ni][rg] = ((float)acc[mi][ni][rg] * (sxr[rg] * sww[ni])) * (1.0f / 16129.0f);
        for (int c = 0; c < ncl; c++) {
            float wo0 = Wo[(wn * 64 + (lane & 31)) * 17 + c];
            float wo1 = Wo[(wn * 64 + 32 + (lane & 31)) * 17 + c];
            #pragma unroll
            for (int rg = 0; rg < 16; rg++) {
                int rowD = (rg & 3) + 8 * (rg >> 2) + 4 * hi;
                float xo = Xo[(wm * 128 + mi * 32 + rowD) * 17 + c];
                vout[0][rg] += xo * wo0;
                vout[1][rg] += xo * wo1;
            }
        }
        #pragma unroll
        for (int ni = 0; ni < 2; ni++) {
            int gcol = bcol + wn * 64 + ni * 32 + (lane & 31);
            #pragma unroll
            for (int rg = 0; rg < 16; rg++) {
                int rowD = (rg & 3) + 8 * (rg >> 2) + 4 * hi;
                int grow = brow + wm * 128 + mi * 32 + rowD;
                float v = vout[ni][rg];
                for (int c2 = 16; c2 < nc; c2++) {   // cold fallback (nc>16 only)
                    int col = cols[c2];
                    v += x[(size_t)grow * DIN + col] *
                         (CB[(size_t)gcol * DIN + col] * SCB[gcol] / 127.0f);
                }
                v += bzz[ni];
                v = __half2float(__float2half(v));
                out[(size_t)grow * DOUT + gcol] = v;
            }
        }
    }
#undef STAGE_HALF
#undef READ_A
#undef READ_B
#undef MFMA16
}

// -------- legacy 128x128 GEMM (fallback: odd shapes / tiny ws) --------
template<int FLY>
__global__ __launch_bounds__(256) void k_gemm(
    const signed char* __restrict__ Xq, const signed char* __restrict__ Wq,
    const float* __restrict__ sx, const float* __restrict__ sw,
    const float* __restrict__ x, const float* __restrict__ CB,
    const float* __restrict__ SCB, const float* __restrict__ bias,
    const unsigned char* __restrict__ bmask,
    const int* __restrict__ ncols, const int* __restrict__ cols,
    float* __restrict__ out, int Nrows, int DOUT, int DIN)
{
    __shared__ __align__(16) signed char Asm[128 * 64];
    __shared__ __align__(16) signed char Bsm[128 * 64];

    int nwg = gridDim.x;
    int bid = blockIdx.x;
    int swzb;
    if ((nwg & 7) == 0) { int cpx = nwg >> 3; swzb = (bid & 7) * cpx + (bid >> 3); }
    else swzb = bid;
    int mtiles = Nrows >> 7;
    int mt = swzb % mtiles;
    int nt = swzb / mtiles;
    int brow = mt << 7, bcol = nt << 7;

    int tid = threadIdx.x, lane = tid & 63, wid = tid >> 6;
    int wr = wid >> 1, wc = wid & 1;

    v4i acc[4][4] = {};

    int arow = wr * 64 + (lane & 15);
    int brl  = wc * 64 + (lane & 15);
    int kc   = (lane >> 4) * 16;

    if constexpr (FLY == 0) {
        int srow = lane >> 2;
        int scol = (lane & 3) * 16;
        const signed char* ga0 = Xq + (size_t)(brow + wid * 16 + srow) * DIN + scol;
        const signed char* ga1 = Xq + (size_t)(brow + (wid + 4) * 16 + srow) * DIN + scol;
        const signed char* gb0 = Wq + (size_t)(bcol + wid * 16 + srow) * DIN + scol;
        const signed char* gb1 = Wq + (size_t)(bcol + (wid + 4) * 16 + srow) * DIN + scol;
        signed char* la0 = &Asm[wid * 1024];
        signed char* la1 = &Asm[(wid + 4) * 1024];
        signed char* lb0 = &Bsm[wid * 1024];
        signed char* lb1 = &Bsm[(wid + 4) * 1024];

        for (int k0 = 0; k0 < DIN; k0 += 64) {
            gld_lds16(ga0 + k0, la0);
            gld_lds16(ga1 + k0, la1);
            gld_lds16(gb0 + k0, lb0);
            gld_lds16(gb1 + k0, lb1);
            __syncthreads();
            v4i a[4], b[4];
            #pragma unroll
            for (int mi = 0; mi < 4; mi++) a[mi] = *(const v4i*)&Asm[(arow + mi * 16) * 64 + kc];
            #pragma unroll
            for (int ni = 0; ni < 4; ni++) b[ni] = *(const v4i*)&Bsm[(brl + ni * 16) * 64 + kc];
            #pragma unroll
            for (int mi = 0; mi < 4; mi++)
                #pragma unroll
                for (int ni = 0; ni < 4; ni++)
                    acc[mi][ni] = __builtin_amdgcn_mfma_i32_16x16x64_i8(a[mi], b[ni], acc[mi][ni], 0, 0, 0);
            __syncthreads();
        }
    } else {
        int ra = tid >> 1, ca = (tid & 1) * 32;
        const float* xrow = x  + (size_t)(brow + ra) * DIN + ca;
        const float* crow = CB + (size_t)(bcol + ra) * DIN + ca;
        float xscale = 127.0f / sx[brow + ra];
        float scb    = SCB[bcol + ra];
        float wscale = 127.0f / sw[bcol + ra];
        signed char* lda = &Asm[ra * 64 + ca];
        signed char* ldb = &Bsm[ra * 64 + ca];

        for (int k0 = 0; k0 < DIN; k0 += 64) {
            float xa[32], wb[32];
            #pragma unroll
            for (int j = 0; j < 8; j++) {
                float4 v = ((const float4*)(xrow + k0))[j];
                xa[4*j] = v.x; xa[4*j+1] = v.y; xa[4*j+2] = v.z; xa[4*j+3] = v.w;
                float4 u = ((const float4*)(crow + k0))[j];
                wb[4*j] = u.x; wb[4*j+1] = u.y; wb[4*j+2] = u.z; wb[4*j+3] = u.w;
            }
            uint4 bm0 = *(const uint4*)(bmask + k0 + ca);
            uint4 bm1 = *(const uint4*)(bmask + k0 + ca + 16);
            const unsigned char* bmp0 = (const unsigned char*)&bm0;
            const unsigned char* bmp1 = (const unsigned char*)&bm1;
            int qa[32], qb[32];
            #pragma unroll
            for (int j = 0; j < 32; j++) {
                float fx = xa[j];
                if ((j < 16 ? bmp0[j] : bmp1[j - 16])) fx = 0.0f;
                float rx = rintf(fx * xscale);
                qa[j] = (int)fminf(127.0f, fmaxf(-127.0f, rx));
                float wv = wb[j] * scb / 127.0f;
                float rw = rintf(wv * wscale);
                qb[j] = (int)fminf(127.0f, fmaxf(-127.0f, rw));
            }
            int4 pa0, pa1, pb0, pb1;
            #pragma unroll
            for (int g = 0; g < 8; g++) {
                int vpk = (qa[4*g]&0xff) | ((qa[4*g+1]&0xff)<<8) | ((qa[4*g+2]&0xff)<<16) | ((qa[4*g+3]&0xff)<<24);
                if (g < 4) ((int*)&pa0)[g] = vpk; else ((int*)&pa1)[g-4] = vpk;
                int wpk = (qb[4*g]&0xff) | ((qb[4*g+1]&0xff)<<8) | ((qb[4*g+2]&0xff)<<16) | ((qb[4*g+3]&0xff)<<24);
                if (g < 4) ((int*)&pb0)[g] = wpk; else ((int*)&pb1)[g-4] = wpk;
            }
            __syncthreads();
            *(int4*)lda = pa0; *(int4*)(lda + 16) = pa1;
            *(int4*)ldb = pb0; *(int4*)(ldb + 16) = pb1;
            __syncthreads();
            v4i a[4], b[4];
            #pragma unroll
            for (int mi = 0; mi < 4; mi++) a[mi] = *(const v4i*)&Asm[(arow + mi * 16) * 64 + kc];
            #pragma unroll
            for (int ni = 0; ni < 4; ni++) b[ni] = *(const v4i*)&Bsm[(brl + ni * 16) * 64 + kc];
            #pragma unroll
            for (int mi = 0; mi < 4; mi++)
                #pragma unroll
                for (int ni = 0; ni < 4; ni++)
                    acc[mi][ni] = __builtin_amdgcn_mfma_i32_16x16x64_i8(a[mi], b[ni], acc[mi][ni], 0, 0, 0);
        }
        __syncthreads();
    }

    int nc = *ncols;
    int ncl = nc < 16 ? nc : 16;
    float* Xo = (float*)Asm;
    float* Wo = (float*)Bsm;
    for (int idx = tid; idx < 2048; idx += 256) {
        int i = idx >> 4, c = idx & 15;
        if (c < ncl) {
            int col = cols[c];
            Xo[idx] = x[(size_t)(brow + i) * DIN + col];
            Wo[idx] = CB[(size_t)(bcol + i) * DIN + col] * SCB[bcol + i] / 127.0f;
        }
    }
    __syncthreads();

    #pragma unroll
    for (int mi = 0; mi < 4; mi++) {
        #pragma unroll
        for (int ni = 0; ni < 4; ni++) {
            int rl0 = wr * 64 + mi * 16 + (lane >> 4) * 4;
            int cl  = wc * 64 + ni * 16 + (lane & 15);
            int gcol = bcol + cl;
            float swv = sw[gcol];
            float bz = bias[gcol];
            #pragma unroll
            for (int r = 0; r < 4; r++) {
                int grow = brow + rl0 + r;
                float v = ((float)acc[mi][ni][r] * (sx[grow] * swv)) * (1.0f / 16129.0f);
                float osum = 0.0f;
                for (int c = 0; c < ncl; c++)
                    osum += Xo[(rl0 + r) * 16 + c] * Wo[cl * 16 + c];
                for (int c = 16; c < nc; c++) {
                    int col = cols[c];
                    osum += x[(size_t)grow * DIN + col] *
                            (CB[(size_t)gcol * DIN + col] * SCB[gcol] / 127.0f);
                }
                v = v + osum;
                v = v + bz;
                v = __half2float(__float2half(v));
                out[(size_t)grow * DOUT + gcol] = v;
            }
        }
    }
}

// ---------------- host launch ----------------
static constexpr size_t FLAGS_OFF = 0;
static constexpr size_t BMASK_OFF = 16384;
static constexpr size_t NCOLS_OFF = 20480;
static constexpr size_t COLS_OFF  = 20544;
static constexpr size_t SX_OFF    = 36992;
static constexpr size_t SW_OFF    = 69760;
static constexpr size_t DYN_OFF   = 262144;

extern "C" void kernel_launch(void* const* d_in, const int* in_sizes, int n_in,
                              void* d_out, int out_size, void* d_ws, size_t ws_size,
                              hipStream_t stream) {
    const float* x    = (const float*)d_in[0];
    const float* CB   = (const float*)d_in[1];
    const float* SCB  = (const float*)d_in[2];
    const float* bias = (const float*)d_in[3];

    int DOUT  = in_sizes[2];
    int DIN   = in_sizes[1] / DOUT;
    int Nrows = in_sizes[0] / DIN;

    char* ws = (char*)d_ws;
    unsigned int* flags = (unsigned int*)(ws + FLAGS_OFF);
    unsigned char* bmask = (unsigned char*)(ws + BMASK_OFF);
    int* ncols = (int*)(ws + NCOLS_OFF);
    int* cols  = (int*)(ws + COLS_OFF);
    float* sx  = (float*)(ws + SX_OFF);
    float* sw  = (float*)(ws + SW_OFF);

    size_t off = DYN_OFF;
    float* Xout = (float*)(ws + off); off += (size_t)Nrows * 16 * 4;
    float* Wout = (float*)(ws + off); off += (size_t)DOUT * 16 * 4;
    signed char* Xq = (signed char*)(ws + off); off += (size_t)Nrows * DIN;
    signed char* Wq = (signed char*)(ws + off); off += (size_t)DOUT * DIN;
    size_t need = off;
    float* out = (float*)d_out;

    bool bigws = ws_size >= need;
    bool can8  = bigws && (Nrows % 256 == 0) && (DOUT % 256 == 0) && (DIN % 256 == 0);

    hipMemsetAsync(ws + FLAGS_OFF, 0, 16384, stream);
    k_flags<<<2048, 256, 0, stream>>>(x, flags, Nrows * DIN / 4, DIN);
    k_build<<<1, 256, 0, stream>>>(flags, bmask, ncols, cols, DIN);
    k_quantx<<<Nrows, 256, 0, stream>>>(x, bmask, bigws ? Xq : nullptr, sx,
                                        Xout, ncols, cols, DIN);
    k_quantw<<<DOUT, 256, 0, stream>>>(CB, SCB, bigws ? Wq : nullptr, sw,
                                       Wout, ncols, cols, DIN);

    if (can8) {
        int ngrid = (Nrows / 256) * (DOUT / 256);
        k_gemm32<<<ngrid, 512, 0, stream>>>(Xq, Wq, sx, sw, x, CB, SCB, bias,
                                            Xout, Wout, ncols, cols, out, Nrows, DOUT, DIN);
    } else if (bigws && (Nrows % 128 == 0) && (DOUT % 128 == 0) && (DIN % 64 == 0)) {
        int ngrid = (Nrows / 128) * (DOUT / 128);
        k_gemm<0><<<ngrid, 256, 0, stream>>>(Xq, Wq, sx, sw, x, CB, SCB, bias,
                                             bmask, ncols, cols, out, Nrows, DOUT, DIN);
    } else {
        int ngrid = (Nrows / 128) * (DOUT / 128);
        k_gemm<1><<<ngrid, 256, 0, stream>>>(nullptr, nullptr, sx, sw, x, CB, SCB, bias,
                                             bmask, ncols, cols, out, Nrows, DOUT, DIN);
    }
}

// Round 16
// 688.651 us; speedup vs baseline: 1.1250x; 1.1250x over previous
//
#include <hip/hip_runtime.h>
#include <hip/hip_fp16.h>
#include <stdint.h>

typedef int v4i __attribute__((ext_vector_type(4)));

__device__ __forceinline__ void gld_lds16(const void* g, void* l) {
    __builtin_amdgcn_global_load_lds(
        (const __attribute__((address_space(1))) void*)g,
        (__attribute__((address_space(3))) void*)l,
        16, 0, 0);
}

#define ENDBAR() do { __builtin_amdgcn_s_barrier(); __builtin_amdgcn_sched_barrier(0); } while (0)
#define VMC(n)   asm volatile("s_waitcnt vmcnt(" #n ")" ::: "memory")
#define VMLG0()  asm volatile("s_waitcnt vmcnt(0) lgkmcnt(0)" ::: "memory")

// ---------------- kernel 1: outlier column flags (|x| > 6.0) ----------------
__global__ __launch_bounds__(256) void k_flags(const float* __restrict__ x,
                                               unsigned int* __restrict__ flags,
                                               int total4, int DIN) {
    int idx = blockIdx.x * blockDim.x + threadIdx.x;
    int stride = gridDim.x * blockDim.x;
    int dmask = DIN - 1;  // DIN pow2
    for (int i = idx; i < total4; i += stride) {
        float4 v = ((const float4*)x)[i];
        int base = i * 4;
        if (fabsf(v.x) > 6.0f) atomicOr(&flags[(base + 0) & dmask], 1u);
        if (fabsf(v.y) > 6.0f) atomicOr(&flags[(base + 1) & dmask], 1u);
        if (fabsf(v.z) > 6.0f) atomicOr(&flags[(base + 2) & dmask], 1u);
        if (fabsf(v.w) > 6.0f) atomicOr(&flags[(base + 3) & dmask], 1u);
    }
}

// ------- kernel 2: byte mask + deterministic ascending compaction -------
__global__ __launch_bounds__(256) void k_build(const unsigned int* __restrict__ flags,
                                               unsigned char* __restrict__ bmask,
                                               int* __restrict__ ncols,
                                               int* __restrict__ cols, int DIN) {
    __shared__ int wcnt[4];
    __shared__ int base;
    int tid = threadIdx.x, lane = tid & 63, wid = tid >> 6;
    if (tid == 0) base = 0;
    __syncthreads();
    for (int c0 = 0; c0 < DIN; c0 += 256) {
        int c = c0 + tid;
        bool p = (c < DIN) && (flags[c] != 0u);
        if (c < DIN) bmask[c] = p ? 1 : 0;
        unsigned long long m = __ballot(p);
        int wpre = __popcll(m & ((1ull << lane) - 1ull));
        if (lane == 0) wcnt[wid] = __popcll(m);
        __syncthreads();
        int pre = 0;
        for (int w = 0; w < wid; w++) pre += wcnt[w];
        if (p) cols[base + pre + wpre] = c;
        __syncthreads();
        if (tid == 0) base += wcnt[0] + wcnt[1] + wcnt[2] + wcnt[3];
        __syncthreads();
    }
    if (tid == 0) *ncols = base;
}

// ------- kernel 3: per-row activation quant + fused Xout panel gather -------
__global__ __launch_bounds__(256) void k_quantx(const float* __restrict__ x,
                                                const unsigned char* __restrict__ bmask,
                                                signed char* __restrict__ Xq,
                                                float* __restrict__ sx,
                                                float* __restrict__ Xout,
                                                const int* __restrict__ ncols,
                                                const int* __restrict__ cols, int DIN) {
    int row = blockIdx.x;
    int tid = threadIdx.x, lane = tid & 63, wid = tid >> 6;
    const float* xr = x + (size_t)row * DIN;
    float f[16];
    #pragma unroll
    for (int j = 0; j < 4; j++) {
        float4 v = ((const float4*)xr)[tid * 4 + j];
        f[4*j] = v.x; f[4*j+1] = v.y; f[4*j+2] = v.z; f[4*j+3] = v.w;
    }
    uint4 bm4 = ((const uint4*)bmask)[tid];
    const unsigned char* bm = (const unsigned char*)&bm4;
    float m = 0.0f;
    #pragma unroll
    for (int j = 0; j < 16; j++) {
        if (bm[j]) f[j] = 0.0f;
        m = fmaxf(m, fabsf(f[j]));
    }
    #pragma unroll
    for (int off = 32; off >= 1; off >>= 1) m = fmaxf(m, __shfl_xor(m, off));
    __shared__ float red[4];
    if (lane == 0) red[wid] = m;
    __syncthreads();
    m = fmaxf(fmaxf(red[0], red[1]), fmaxf(red[2], red[3]));
    float sxv = fmaxf(m, 1e-8f);
    if (Xq) {
        float scale = 127.0f / sxv;
        int qi[16];
        #pragma unroll
        for (int j = 0; j < 16; j++) {
            float r = rintf(f[j] * scale);
            r = fminf(127.0f, fmaxf(-127.0f, r));
            qi[j] = (int)r;
        }
        int4 ov;
        ov.x = (qi[0]&0xff) | ((qi[1]&0xff)<<8) | ((qi[2]&0xff)<<16) | ((qi[3]&0xff)<<24);
        ov.y = (qi[4]&0xff) | ((qi[5]&0xff)<<8) | ((qi[6]&0xff)<<16) | ((qi[7]&0xff)<<24);
        ov.z = (qi[8]&0xff) | ((qi[9]&0xff)<<8) | ((qi[10]&0xff)<<16) | ((qi[11]&0xff)<<24);
        ov.w = (qi[12]&0xff) | ((qi[13]&0xff)<<8) | ((qi[14]&0xff)<<16) | ((qi[15]&0xff)<<24);
        ((int4*)(Xq + (size_t)row * DIN))[tid] = ov;
    }
    if (tid < 16) {
        int nc = *ncols;
        int ncl = nc < 16 ? nc : 16;
        float v = 0.0f;
        if (tid < ncl) v = xr[cols[tid]];       // row L1-hot; original (unzeroed) x
        Xout[(size_t)row * 16 + tid] = v;
    }
    if (tid == 0) sx[row] = sxv;
}

// ------- kernel 4: per-output-row weight quant + fused Wout panel gather -------
__global__ __launch_bounds__(256) void k_quantw(const float* __restrict__ CB,
                                                const float* __restrict__ SCB,
                                                signed char* __restrict__ Wq,
                                                float* __restrict__ sw,
                                                float* __restrict__ Wout,
                                                const int* __restrict__ ncols,
                                                const int* __restrict__ cols, int DIN) {
    int row = blockIdx.x;
    int tid = threadIdx.x, lane = tid & 63, wid = tid >> 6;
    float scb = SCB[row];
    const float* cr = CB + (size_t)row * DIN;
    float w[16];
    #pragma unroll
    for (int j = 0; j < 4; j++) {
        float4 v = ((const float4*)cr)[tid * 4 + j];
        w[4*j]   = v.x * scb / 127.0f;
        w[4*j+1] = v.y * scb / 127.0f;
        w[4*j+2] = v.z * scb / 127.0f;
        w[4*j+3] = v.w * scb / 127.0f;
    }
    float m = 0.0f;
    #pragma unroll
    for (int j = 0; j < 16; j++) m = fmaxf(m, fabsf(w[j]));
    #pragma unroll
    for (int off = 32; off >= 1; off >>= 1) m = fmaxf(m, __shfl_xor(m, off));
    __shared__ float red[4];
    if (lane == 0) red[wid] = m;
    __syncthreads();
    m = fmaxf(fmaxf(red[0], red[1]), fmaxf(red[2], red[3]));
    float swv = fmaxf(m, 1e-8f);
    if (Wq) {
        float scale = 127.0f / swv;
        int qi[16];
        #pragma unroll
        for (int j = 0; j < 16; j++) {
            float r = rintf(w[j] * scale);
            r = fminf(127.0f, fmaxf(-127.0f, r));
            qi[j] = (int)r;
        }
        int4 ov;
        ov.x = (qi[0]&0xff) | ((qi[1]&0xff)<<8) | ((qi[2]&0xff)<<16) | ((qi[3]&0xff)<<24);
        ov.y = (qi[4]&0xff) | ((qi[5]&0xff)<<8) | ((qi[6]&0xff)<<16) | ((qi[7]&0xff)<<24);
        ov.z = (qi[8]&0xff) | ((qi[9]&0xff)<<8) | ((qi[10]&0xff)<<16) | ((qi[11]&0xff)<<24);
        ov.w = (qi[12]&0xff) | ((qi[13]&0xff)<<8) | ((qi[14]&0xff)<<16) | ((qi[15]&0xff)<<24);
        ((int4*)(Wq + (size_t)row * DIN))[tid] = ov;
    }
    if (tid < 16) {
        int nc = *ncols;
        int ncl = nc < 16 ? nc : 16;
        float v = 0.0f;
        if (tid < ncl) v = cr[cols[tid]] * scb / 127.0f;   // row L1-hot
        Wout[(size_t)row * 16 + tid] = v;
    }
    if (tid == 0) sw[row] = swv;
}

// -------- kernel 5: 256x256 int8 GEMM, merged 2-phase windows (R10 structure) --------
__global__ __launch_bounds__(512) void k_gemm8(
    const signed char* __restrict__ Xq, const signed char* __restrict__ Wq,
    const float* __restrict__ sx, const float* __restrict__ sw,
    const float* __restrict__ x, const float* __restrict__ CB,
    const float* __restrict__ SCB, const float* __restrict__ bias,
    const float* __restrict__ Xout, const float* __restrict__ Wout,
    const int* __restrict__ ncols, const int* __restrict__ cols,
    float* __restrict__ out, int Nrows, int DOUT, int DIN)
{
    // A: [buf][256 rows][128B], swizzle: byte-in-row ^= 16*((row>>1)&7). B at +65536.
    __shared__ __align__(16) char LDS[131072];

    const int tid = threadIdx.x, lane = tid & 63, wid = tid >> 6;
    const int wm = wid >> 2, wn = wid & 3;

    int nwg = gridDim.x, bid = blockIdx.x;
    int swzb;
    if ((nwg & 7) == 0) { int cpx = nwg >> 3; swzb = (bid & 7) * cpx + (bid >> 3); }
    else swzb = bid;
    int mtiles = Nrows >> 8;
    int ntiles = DOUT >> 8;
    int mt, ntl;
    if ((mtiles & 7) == 0 && (ntiles & 3) == 0 && (nwg & 31) == 0) {
        // co-resident 32 blocks form an 8x4 (mt x ntl) rectangle for L2 reuse
        int group = swzb >> 5, local = swzb & 31;
        int mrects = mtiles >> 3;
        int mt_r = group % mrects, nt_r = group / mrects;
        mt  = (mt_r << 3) + (local & 7);
        ntl = (nt_r << 2) + (local >> 3);
    } else {
        mt = swzb % mtiles; ntl = swzb / mtiles;
    }
    int brow = mt << 8, bcol = ntl << 8;

    // ds-read lane constants: slot ^= (row>>1)&7, row&15 == lane&15
    const int o0 = 16 * ((lane >> 4) ^ ((lane >> 1) & 7));
    const int o1 = o0 ^ 64;
    const int aRow = (wm * 128 + (lane & 15)) * 128;
    const int bRow = (wn * 64 + (lane & 15)) * 128;

    // stage: LDS dest linear; global source pre-swizzled with the same involution
    const int stRow = wid * 8 + (lane >> 3);
    const int stCol = 16 * ((lane & 7) ^ (((wid & 1) << 2) + (lane >> 4)));
    const signed char* aSrc = Xq + (size_t)(brow + stRow) * DIN + stCol;
    const signed char* bSrc = Wq + (size_t)(bcol + stRow) * DIN + stCol;
    const int ldsW = wid * 1024;

    v4i acc[8][4] = {};
    v4i a0[8], a1[8], b0[4], b1[4];

    const int nt = DIN >> 7;      // 128-byte K-tiles
    const int NIT = nt >> 1;      // 2 tiles per iteration

#define STAGE_HALF(srcBase, matOff, bf, h, kc)                                   \
    do { _Pragma("unroll")                                                        \
      for (int q = 0; q < 2; q++) {                                               \
        int seg = 2*(h) + q;                                                      \
        gld_lds16((srcBase) + (size_t)seg * 64 * DIN + (kc),                      \
                  &LDS[(matOff) + (bf)*32768 + seg*8192 + ldsW]);                 \
      }                                                                           \
    } while (0)

#define DS_A(dst, bf, miB)                                                        \
    do { _Pragma("unroll")                                                        \
      for (int mi = 0; mi < 4; mi++) {                                            \
        int ro = (bf)*32768 + aRow + ((miB) + mi) * 2048;                         \
        dst[mi*2+0] = *(const v4i*)&LDS[ro + o0];                                 \
        dst[mi*2+1] = *(const v4i*)&LDS[ro + o1];                                 \
      }                                                                           \
    } while (0)

#define DS_B(dst, bf, niB)                                                        \
    do { _Pragma("unroll")                                                        \
      for (int ni = 0; ni < 2; ni++) {                                            \
        int ro = 65536 + (bf)*32768 + bRow + ((niB) + ni) * 2048;                 \
        dst[ni*2+0] = *(const v4i*)&LDS[ro + o0];                                 \
        dst[ni*2+1] = *(const v4i*)&LDS[ro + o1];                                 \
      }                                                                           \
    } while (0)

#define QUAD(A8, B4, accM, accN)                                                  \
    do { __builtin_amdgcn_s_setprio(1); _Pragma("unroll")                         \
      for (int mi = 0; mi < 4; mi++) { _Pragma("unroll")                          \
        for (int ni = 0; ni < 2; ni++) { _Pragma("unroll")                        \
          for (int ks = 0; ks < 2; ks++)                                          \
            acc[(accM)+mi][(accN)+ni] = __builtin_amdgcn_mfma_i32_16x16x64_i8(    \
                A8[mi*2+ks], B4[ni*2+ks], acc[(accM)+mi][(accN)+ni], 0, 0, 0);    \
        } }                                                                       \
      __builtin_amdgcn_s_setprio(0);                                              \
    } while (0)

    // ---- prologue: tile0 -> buf0, A(1) -> buf1; leave A(1) in flight ----
    STAGE_HALF(aSrc, 0,     0, 0, 0);
    STAGE_HALF(aSrc, 0,     0, 1, 0);
    STAGE_HALF(bSrc, 65536, 0, 0, 0);
    STAGE_HALF(bSrc, 65536, 0, 1, 0);
    STAGE_HALF(aSrc, 0,     1, 0, 128);
    STAGE_HALF(aSrc, 0,     1, 1, 128);
    VMC(4);
    ENDBAR();

    for (int it = 0; it < NIT; ++it) {
        int t = 2 * it;
        int kB1 = (t + 1) << 7;
        int tA2 = t + 2; if (tA2 > nt - 1) tA2 = nt - 1;
        int kA2 = tA2 << 7;
        int tA3 = t + 3; if (tA3 > nt - 1) tA3 = nt - 1;
        int kA3 = tA3 << 7;

        // window {ph1,ph2}: stage buf1-B (disjoint from buf0 reads); no mid-barrier
        STAGE_HALF(bSrc, 65536, 1, 0, kB1);
        DS_B(b0, 0, 0); DS_A(a0, 0, 0);
        QUAD(a0, b0, 0, 0);
        STAGE_HALF(bSrc, 65536, 1, 1, kB1);
        DS_A(a1, 0, 4);
        QUAD(a1, b0, 4, 0);
        ENDBAR();
        // window {ph3,ph4}: stage buf0-A (disjoint from buf0-B reads)
        STAGE_HALF(aSrc, 0, 0, 0, kA2);
        DS_B(b1, 0, 2);
        QUAD(a1, b1, 4, 2);
        STAGE_HALF(aSrc, 0, 0, 1, kA2);
        QUAD(a0, b1, 0, 2);
        VMC(4);
        ENDBAR();
        // window {ph5,ph6}: stage buf0-B (disjoint from buf1 reads)
        STAGE_HALF(bSrc, 65536, 0, 0, kA2);
        DS_B(b0, 1, 0); DS_A(a0, 1, 0);
        QUAD(a0, b0, 0, 0);
        STAGE_HALF(bSrc, 65536, 0, 1, kA2);
        DS_A(a1, 1, 4);
        QUAD(a1, b0, 4, 0);
        ENDBAR();
        // window {ph7,ph8}: stage buf1-A (disjoint from buf1-B reads)
        STAGE_HALF(aSrc, 0, 1, 0, kA3);
        DS_B(b1, 1, 2);
        QUAD(a1, b1, 4, 2);
        STAGE_HALF(aSrc, 0, 1, 1, kA3);
        QUAD(a0, b1, 0, 2);
        VMC(4);
        ENDBAR();
    }
    VMLG0();
    ENDBAR();

    // ---- epilogue: rank-ncl outlier update, c-outer, two mi-halves ----
    int nc = *ncols;
    int ncl = nc < 16 ? nc : 16;
    float* Xo = (float*)&LDS[0];            // [256][17]
    float* Wo = (float*)&LDS[65536];        // [256][17]
    for (int idx = tid; idx < 4096; idx += 512) {
        int i = idx >> 4, c = idx & 15;
        Xo[i * 17 + c] = Xout[(size_t)(brow + i) * 16 + c];
        Wo[i * 17 + c] = Wout[(size_t)(bcol + i) * 16 + c];
    }
    __syncthreads();

    float sww[4], bzz[4];
    #pragma unroll
    for (int ni = 0; ni < 4; ni++) {
        int gcol = bcol + wn * 64 + ni * 16 + (lane & 15);
        sww[ni] = sw[gcol];
        bzz[ni] = bias[gcol];
    }

    #pragma unroll
    for (int h = 0; h < 2; h++) {
        float vout[4][4][4];
        #pragma unroll
        for (int mi = 0; mi < 4; mi++) {
            int row = wm * 128 + (h * 4 + mi) * 16 + (lane >> 4) * 4;
            #pragma unroll
            for (int r = 0; r < 4; r++) {
                float sxv = sx[brow + row + r];
                #pragma unroll
                for (int ni = 0; ni < 4; ni++)
                    vout[mi][ni][r] =
                        ((float)acc[h * 4 + mi][ni][r] * (sxv * sww[ni])) * (1.0f / 16129.0f);
            }
        }
        for (int c = 0; c < ncl; c++) {
            float wo[4];
            #pragma unroll
            for (int ni = 0; ni < 4; ni++)
                wo[ni] = Wo[(wn * 64 + ni * 16 + (lane & 15)) * 17 + c];
            #pragma unroll
            for (int mi = 0; mi < 4; mi++) {
                int row = wm * 128 + (h * 4 + mi) * 16 + (lane >> 4) * 4;
                #pragma unroll
                for (int r = 0; r < 4; r++) {
                    float xo = Xo[(row + r) * 17 + c];
                    #pragma unroll
                    for (int ni = 0; ni < 4; ni++)
                        vout[mi][ni][r] += xo * wo[ni];
                }
            }
        }
        #pragma unroll
        for (int mi = 0; mi < 4; mi++) {
            #pragma unroll
            for (int ni = 0; ni < 4; ni++) {
                int gcol = bcol + wn * 64 + ni * 16 + (lane & 15);
                #pragma unroll
                for (int r = 0; r < 4; r++) {
                    int grow = brow + wm * 128 + (h * 4 + mi) * 16 + (lane >> 4) * 4 + r;
                    float v = vout[mi][ni][r];
                    for (int c = 16; c < nc; c++) {   // cold fallback (nc>16 only)
                        int col = cols[c];
                        v += x[(size_t)grow * DIN + col] *
                             (CB[(size_t)gcol * DIN + col] * SCB[gcol] / 127.0f);
                    }
                    v += bzz[ni];
                    v = __half2float(__float2half(v));
                    out[(size_t)grow * DOUT + gcol] = v;
                }
            }
        }
    }
#undef STAGE_HALF
#undef DS_A
#undef DS_B
#undef QUAD
}

// -------- legacy 128x128 GEMM (fallback: odd shapes / tiny ws) --------
template<int FLY>
__global__ __launch_bounds__(256) void k_gemm(
    const signed char* __restrict__ Xq, const signed char* __restrict__ Wq,
    const float* __restrict__ sx, const float* __restrict__ sw,
    const float* __restrict__ x, const float* __restrict__ CB,
    const float* __restrict__ SCB, const float* __restrict__ bias,
    const unsigned char* __restrict__ bmask,
    const int* __restrict__ ncols, const int* __restrict__ cols,
    float* __restrict__ out, int Nrows, int DOUT, int DIN)
{
    __shared__ __align__(16) signed char Asm[128 * 64];
    __shared__ __align__(16) signed char Bsm[128 * 64];

    int nwg = gridDim.x;
    int bid = blockIdx.x;
    int swzb;
    if ((nwg & 7) == 0) { int cpx = nwg >> 3; swzb = (bid & 7) * cpx + (bid >> 3); }
    else swzb = bid;
    int mtiles = Nrows >> 7;
    int mt = swzb % mtiles;
    int nt = swzb / mtiles;
    int brow = mt << 7, bcol = nt << 7;

    int tid = threadIdx.x, lane = tid & 63, wid = tid >> 6;
    int wr = wid >> 1, wc = wid & 1;

    v4i acc[4][4] = {};

    int arow = wr * 64 + (lane & 15);
    int brl  = wc * 64 + (lane & 15);
    int kc   = (lane >> 4) * 16;

    if constexpr (FLY == 0) {
        int srow = lane >> 2;
        int scol = (lane & 3) * 16;
        const signed char* ga0 = Xq + (size_t)(brow + wid * 16 + srow) * DIN + scol;
        const signed char* ga1 = Xq + (size_t)(brow + (wid + 4) * 16 + srow) * DIN + scol;
        const signed char* gb0 = Wq + (size_t)(bcol + wid * 16 + srow) * DIN + scol;
        const signed char* gb1 = Wq + (size_t)(bcol + (wid + 4) * 16 + srow) * DIN + scol;
        signed char* la0 = &Asm[wid * 1024];
        signed char* la1 = &Asm[(wid + 4) * 1024];
        signed char* lb0 = &Bsm[wid * 1024];
        signed char* lb1 = &Bsm[(wid + 4) * 1024];

        for (int k0 = 0; k0 < DIN; k0 += 64) {
            gld_lds16(ga0 + k0, la0);
            gld_lds16(ga1 + k0, la1);
            gld_lds16(gb0 + k0, lb0);
            gld_lds16(gb1 + k0, lb1);
            __syncthreads();
            v4i a[4], b[4];
            #pragma unroll
            for (int mi = 0; mi < 4; mi++) a[mi] = *(const v4i*)&Asm[(arow + mi * 16) * 64 + kc];
            #pragma unroll
            for (int ni = 0; ni < 4; ni++) b[ni] = *(const v4i*)&Bsm[(brl + ni * 16) * 64 + kc];
            #pragma unroll
            for (int mi = 0; mi < 4; mi++)
                #pragma unroll
                for (int ni = 0; ni < 4; ni++)
                    acc[mi][ni] = __builtin_amdgcn_mfma_i32_16x16x64_i8(a[mi], b[ni], acc[mi][ni], 0, 0, 0);
            __syncthreads();
        }
    } else {
        int ra = tid >> 1, ca = (tid & 1) * 32;
        const float* xrow = x  + (size_t)(brow + ra) * DIN + ca;
        const float* crow = CB + (size_t)(bcol + ra) * DIN + ca;
        float xscale = 127.0f / sx[brow + ra];
        float scb    = SCB[bcol + ra];
        float wscale = 127.0f / sw[bcol + ra];
        signed char* lda = &Asm[ra * 64 + ca];
        signed char* ldb = &Bsm[ra * 64 + ca];

        for (int k0 = 0; k0 < DIN; k0 += 64) {
            float xa[32], wb[32];
            #pragma unroll
            for (int j = 0; j < 8; j++) {
                float4 v = ((const float4*)(xrow + k0))[j];
                xa[4*j] = v.x; xa[4*j+1] = v.y; xa[4*j+2] = v.z; xa[4*j+3] = v.w;
                float4 u = ((const float4*)(crow + k0))[j];
                wb[4*j] = u.x; wb[4*j+1] = u.y; wb[4*j+2] = u.z; wb[4*j+3] = u.w;
            }
            uint4 bm0 = *(const uint4*)(bmask + k0 + ca);
            uint4 bm1 = *(const uint4*)(bmask + k0 + ca + 16);
            const unsigned char* bmp0 = (const unsigned char*)&bm0;
            const unsigned char* bmp1 = (const unsigned char*)&bm1;
            int qa[32], qb[32];
            #pragma unroll
            for (int j = 0; j < 32; j++) {
                float fx = xa[j];
                if ((j < 16 ? bmp0[j] : bmp1[j - 16])) fx = 0.0f;
                float rx = rintf(fx * xscale);
                qa[j] = (int)fminf(127.0f, fmaxf(-127.0f, rx));
                float wv = wb[j] * scb / 127.0f;
                float rw = rintf(wv * wscale);
                qb[j] = (int)fminf(127.0f, fmaxf(-127.0f, rw));
            }
            int4 pa0, pa1, pb0, pb1;
            #pragma unroll
            for (int g = 0; g < 8; g++) {
                int vpk = (qa[4*g]&0xff) | ((qa[4*g+1]&0xff)<<8) | ((qa[4*g+2]&0xff)<<16) | ((qa[4*g+3]&0xff)<<24);
                if (g < 4) ((int*)&pa0)[g] = vpk; else ((int*)&pa1)[g-4] = vpk;
                int wpk = (qb[4*g]&0xff) | ((qb[4*g+1]&0xff)<<8) | ((qb[4*g+2]&0xff)<<16) | ((qb[4*g+3]&0xff)<<24);
                if (g < 4) ((int*)&pb0)[g] = wpk; else ((int*)&pb1)[g-4] = wpk;
            }
            __syncthreads();
            *(int4*)lda = pa0; *(int4*)(lda + 16) = pa1;
            *(int4*)ldb = pb0; *(int4*)(ldb + 16) = pb1;
            __syncthreads();
            v4i a[4], b[4];
            #pragma unroll
            for (int mi = 0; mi < 4; mi++) a[mi] = *(const v4i*)&Asm[(arow + mi * 16) * 64 + kc];
            #pragma unroll
            for (int ni = 0; ni < 4; ni++) b[ni] = *(const v4i*)&Bsm[(brl + ni * 16) * 64 + kc];
            #pragma unroll
            for (int mi = 0; mi < 4; mi++)
                #pragma unroll
                for (int ni = 0; ni < 4; ni++)
                    acc[mi][ni] = __builtin_amdgcn_mfma_i32_16x16x64_i8(a[mi], b[ni], acc[mi][ni], 0, 0, 0);
        }
        __syncthreads();
    }

    int nc = *ncols;
    int ncl = nc < 16 ? nc : 16;
    float* Xo = (float*)Asm;
    float* Wo = (float*)Bsm;
    for (int idx = tid; idx < 2048; idx += 256) {
        int i = idx >> 4, c = idx & 15;
        if (c < ncl) {
            int col = cols[c];
            Xo[idx] = x[(size_t)(brow + i) * DIN + col];
            Wo[idx] = CB[(size_t)(bcol + i) * DIN + col] * SCB[bcol + i] / 127.0f;
        }
    }
    __syncthreads();

    #pragma unroll
    for (int mi = 0; mi < 4; mi++) {
        #pragma unroll
        for (int ni = 0; ni < 4; ni++) {
            int rl0 = wr * 64 + mi * 16 + (lane >> 4) * 4;
            int cl  = wc * 64 + ni * 16 + (lane & 15);
            int gcol = bcol + cl;
            float swv = sw[gcol];
            float bz = bias[gcol];
            #pragma unroll
            for (int r = 0; r < 4; r++) {
                int grow = brow + rl0 + r;
                float v = ((float)acc[mi][ni][r] * (sx[grow] * swv)) * (1.0f / 16129.0f);
                float osum = 0.0f;
                for (int c = 0; c < ncl; c++)
                    osum += Xo[(rl0 + r) * 16 + c] * Wo[cl * 16 + c];
                for (int c = 16; c < nc; c++) {
                    int col = cols[c];
                    osum += x[(size_t)grow * DIN + col] *
                            (CB[(size_t)gcol * DIN + col] * SCB[gcol] / 127.0f);
                }
                v = v + osum;
                v = v + bz;
                v = __half2float(__float2half(v));
                out[(size_t)grow * DOUT + gcol] = v;
            }
        }
    }
}

// ---------------- host launch ----------------
static constexpr size_t FLAGS_OFF = 0;
static constexpr size_t BMASK_OFF = 16384;
static constexpr size_t NCOLS_OFF = 20480;
static constexpr size_t COLS_OFF  = 20544;
static constexpr size_t SX_OFF    = 36992;
static constexpr size_t SW_OFF    = 69760;
static constexpr size_t DYN_OFF   = 262144;

extern "C" void kernel_launch(void* const* d_in, const int* in_sizes, int n_in,
                              void* d_out, int out_size, void* d_ws, size_t ws_size,
                              hipStream_t stream) {
    const float* x    = (const float*)d_in[0];
    const float* CB   = (const float*)d_in[1];
    const float* SCB  = (const float*)d_in[2];
    const float* bias = (const float*)d_in[3];

    int DOUT  = in_sizes[2];
    int DIN   = in_sizes[1] / DOUT;
    int Nrows = in_sizes[0] / DIN;

    char* ws = (char*)d_ws;
    unsigned int* flags = (unsigned int*)(ws + FLAGS_OFF);
    unsigned char* bmask = (unsigned char*)(ws + BMASK_OFF);
    int* ncols = (int*)(ws + NCOLS_OFF);
    int* cols  = (int*)(ws + COLS_OFF);
    float* sx  = (float*)(ws + SX_OFF);
    float* sw  = (float*)(ws + SW_OFF);

    size_t off = DYN_OFF;
    float* Xout = (float*)(ws + off); off += (size_t)Nrows * 16 * 4;
    float* Wout = (float*)(ws + off); off += (size_t)DOUT * 16 * 4;
    signed char* Xq = (signed char*)(ws + off); off += (size_t)Nrows * DIN;
    signed char* Wq = (signed char*)(ws + off); off += (size_t)DOUT * DIN;
    size_t need = off;
    float* out = (float*)d_out;

    bool bigws = ws_size >= need;
    bool can8  = bigws && (Nrows % 256 == 0) && (DOUT % 256 == 0) && (DIN % 256 == 0);

    hipMemsetAsync(ws + FLAGS_OFF, 0, 16384, stream);
    k_flags<<<2048, 256, 0, stream>>>(x, flags, Nrows * DIN / 4, DIN);
    k_build<<<1, 256, 0, stream>>>(flags, bmask, ncols, cols, DIN);
    k_quantx<<<Nrows, 256, 0, stream>>>(x, bmask, bigws ? Xq : nullptr, sx,
                                        Xout, ncols, cols, DIN);
    k_quantw<<<DOUT, 256, 0, stream>>>(CB, SCB, bigws ? Wq : nullptr, sw,
                                       Wout, ncols, cols, DIN);

    if (can8) {
        int ngrid = (Nrows / 256) * (DOUT / 256);
        k_gemm8<<<ngrid, 512, 0, stream>>>(Xq, Wq, sx, sw, x, CB, SCB, bias,
                                           Xout, Wout, ncols, cols, out, Nrows, DOUT, DIN);
    } else if (bigws && (Nrows % 128 == 0) && (DOUT % 128 == 0) && (DIN % 64 == 0)) {
        int ngrid = (Nrows / 128) * (DOUT / 128);
        k_gemm<0><<<ngrid, 256, 0, stream>>>(Xq, Wq, sx, sw, x, CB, SCB, bias,
                                             bmask, ncols, cols, out, Nrows, DOUT, DIN);
    } else {
        int ngrid = (Nrows / 128) * (DOUT / 128);
        k_gemm<1><<<ngrid, 256, 0, stream>>>(nullptr, nullptr, sx, sw, x, CB, SCB, bias,
                                             bmask, ncols, cols, out, Nrows, DOUT, DIN);
    }
}